// Round 10
// baseline (106.241 us; speedup 1.0000x reference)
//
#include <hip/hip_runtime.h>
#include <hip/hip_fp16.h>

#define SEQ 2048
#define NBH 32
#define C1f 0.09016844005556021f   // log2(e)/16

typedef _Float16 f16x8 __attribute__((ext_vector_type(8)));
typedef __fp16 fp16x2 __attribute__((ext_vector_type(2)));
typedef float f32x4 __attribute__((ext_vector_type(4)));
typedef __attribute__((address_space(1))) const unsigned GASU;
typedef __attribute__((address_space(3))) unsigned LASU;

union U16 { fp16x2 h[4]; f16x8 v; };

__device__ __forceinline__ void gll16(const void* g, void* l) {
  __builtin_amdgcn_global_load_lds((GASU*)g, (LASU*)l, 16, 0, 0);
}

// ======== prep: projection (x<2048) + V transpose (x>=2048) ========
// phik pre-scaled by sqrt(ekn)/8 so d^2 = energy^2*ekn; ckn = 1e-5*ekn.
__global__ __launch_bounds__(256) void prep(
    const float* __restrict__ qg, const float* __restrict__ kg,
    const float* __restrict__ vg, const float* __restrict__ Wg,
    const float* __restrict__ bg,
    __half* __restrict__ phiq, __half* __restrict__ phik,
    __half* __restrict__ vt, float* __restrict__ ckn) {
  __shared__ __align__(16) float smem[64 * 68 + 64 * 64];
  const int x = blockIdx.x;
  const int tid = threadIdx.x;
  if (x >= 2048) {                       // ---- V transpose ----
    const int i = x - 2048;
    const int bh = i >> 5, s0 = (i & 31) * 64;
    float* t = smem;                     // [64][65]
    const float* base = vg + ((long)bh * SEQ + s0) * 64;
    #pragma unroll
    for (int i2 = 0; i2 < 4; ++i2) {
      int seg = i2 * 256 + tid;
      int srow = seg >> 4, sc4 = (seg & 15) << 2;
      float4 xv = *(const float4*)(base + srow * 64 + sc4);
      t[srow * 65 + sc4 + 0] = xv.x; t[srow * 65 + sc4 + 1] = xv.y;
      t[srow * 65 + sc4 + 2] = xv.z; t[srow * 65 + sc4 + 3] = xv.w;
    }
    __syncthreads();
    int d = tid >> 2, sc = (tid & 3) << 4;
    __half tmp[16];
    #pragma unroll
    for (int j = 0; j < 16; ++j) tmp[j] = __float2half(t[(sc + j) * 65 + d]);
    __half* dst = vt + ((long)bh * 64 + d) * SEQ + s0 + sc;
    *(uint4*)dst = *(uint4*)&tmp[0];
    *(uint4*)(dst + 8) = *(uint4*)&tmp[8];
    return;
  }
  // ---- projection ----
  const int wave = tid >> 6, lane = tid & 63;
  const int g = lane >> 4, ql = lane & 15;
  const int isk = x >= 1024;
  const long rowblk = (long)(x & 1023) * 64;
  const float* src = isk ? kg : qg;
  __half* dphi = isk ? phik : phiq;
  float* w_l = smem;                     // [64][68] W^T fp32
  float* x_l = smem + 64 * 68;

  #pragma unroll
  for (int i2 = 0; i2 < 4; ++i2) {       // stage W transposed
    int seg = i2 * 256 + tid;
    int d = seg >> 4, rc = (seg & 15) << 2;
    float4 wv = *(const float4*)(Wg + d * 64 + rc);
    w_l[(rc + 0) * 68 + d] = wv.x; w_l[(rc + 1) * 68 + d] = wv.y;
    w_l[(rc + 2) * 68 + d] = wv.z; w_l[(rc + 3) * 68 + d] = wv.w;
  }
  const float* xb = src + rowblk * 64;
  #pragma unroll
  for (int i2 = 0; i2 < 4; ++i2) {       // stage x (swizzled)
    int seg = i2 * 256 + tid;
    int row = seg >> 4;
    int off = ((seg & 15) * 4) ^ ((row & 7) << 2);
    gll16(xb + row * 64 + off, &x_l[seg * 4]);
  }
  float bias[4];
  #pragma unroll
  for (int rt = 0; rt < 4; ++rt) bias[rt] = bg[rt * 16 + ql];
  __syncthreads();

  f16x8 bh_[2][4], bl_[2][4];            // W hi/lo frags from LDS
  #pragma unroll
  for (int rt = 0; rt < 4; ++rt)
    #pragma unroll
    for (int ks = 0; ks < 2; ++ks) {
      f32x4 wa = *(const f32x4*)&w_l[(rt * 16 + ql) * 68 + ks * 32 + g * 8];
      f32x4 wb = *(const f32x4*)&w_l[(rt * 16 + ql) * 68 + ks * 32 + g * 8 + 4];
      #pragma unroll
      for (int j = 0; j < 4; ++j) {
        float w0 = wa[j]; _Float16 h0 = (_Float16)w0;
        bh_[ks][rt][j] = h0; bl_[ks][rt][j] = (_Float16)(w0 - (float)h0);
        float w1 = wb[j]; _Float16 h1 = (_Float16)w1;
        bh_[ks][rt][4 + j] = h1; bl_[ks][rt][4 + j] = (_Float16)(w1 - (float)h1);
      }
    }

  const int rl = wave * 16 + ql;
  float xv[16];
  #pragma unroll
  for (int ks = 0; ks < 2; ++ks)
    #pragma unroll
    for (int h = 0; h < 2; ++h) {
      int fi = (rl * 64 + ks * 32 + g * 8 + h * 4) ^ ((ql & 7) << 2);
      f32x4 u = *(const f32x4*)&x_l[fi];
      #pragma unroll
      for (int j = 0; j < 4; ++j) xv[ks * 8 + h * 4 + j] = u[j];
    }
  float nn = 0.f;
  #pragma unroll
  for (int j = 0; j < 16; ++j) nn = fmaf(xv[j], xv[j], nn);
  nn += __shfl_xor(nn, 16);
  nn += __shfl_xor(nn, 32);
  if (isk && g == 0) ckn[rowblk + rl] = 1e-5f * exp2f(nn * C1f);
  float scl = isk ? exp2f(nn * (C1f * 0.5f)) * 0.125f : 0.125f;
  float s4[4];
  #pragma unroll
  for (int i2 = 0; i2 < 4; ++i2) s4[i2] = __shfl(scl, (lane & 48) | (g * 4 + i2));

  f16x8 ah[2], al[2];
  #pragma unroll
  for (int ks = 0; ks < 2; ++ks)
    #pragma unroll
    for (int j = 0; j < 8; ++j) {
      float v = xv[ks * 8 + j];
      _Float16 hv = (_Float16)v;
      ah[ks][j] = hv;
      al[ks][j] = (_Float16)(v - (float)hv);
    }
  f32x4 sacc[4] = {};
  #pragma unroll
  for (int ks = 0; ks < 2; ++ks)
    #pragma unroll
    for (int rt = 0; rt < 4; ++rt) {
      sacc[rt] = __builtin_amdgcn_mfma_f32_16x16x32_f16(ah[ks], bh_[ks][rt], sacc[rt], 0, 0, 0);
      sacc[rt] = __builtin_amdgcn_mfma_f32_16x16x32_f16(al[ks], bh_[ks][rt], sacc[rt], 0, 0, 0);
      sacc[rt] = __builtin_amdgcn_mfma_f32_16x16x32_f16(ah[ks], bl_[ks][rt], sacc[rt], 0, 0, 0);
    }
  #pragma unroll
  for (int rt = 0; rt < 4; ++rt)
    #pragma unroll
    for (int i2 = 0; i2 < 4; ++i2) {
      float wq = sacc[rt][i2] + bias[rt];
      float sv, cv;
      __sincosf(wq, &sv, &cv);
      long row = rowblk + wave * 16 + g * 4 + i2;
      dphi[row * 128 + rt * 16 + ql] = __float2half(cv * s4[i2]);
      dphi[row * 128 + 64 + rt * 16 + ql] = __float2half(sv * s4[i2]);
    }
}

// ======== attn: 64q blocks, waves = qh x kh, balanced per-CU quads ========
__global__ __launch_bounds__(256, 4) void attn_kernel(
    const __half* __restrict__ phiq_g, const __half* __restrict__ phik_g,
    const __half* __restrict__ vt_g, const float* __restrict__ ckn_g,
    float* __restrict__ out) {
  const int x = blockIdx.x;
  // Balanced quad assignment: XCD = x&7, slot g2 = (x>>3)&31, batch = x>>8.
  // CU (XCD,g2) gets batches {31-g2, g2, 31-g2, g2} -> 66 tile-steps each.
  // Within a batch all 32 CUs of an XCD share one bh -> L2-resident phik/vt.
  const int g2 = (x >> 3) & 31;
  const int batch = x >> 8;
  const int bh = ((x & 7) << 2) | batch;
  const int s = (batch & 1) ? g2 : (31 - g2);
  const int tid = threadIdx.x;
  const int wv = tid >> 6, lane = tid & 63;
  const int g = lane >> 4, ql = lane & 15;
  const int qh = wv & 1, kh = wv >> 1;
  const long rowbase = (long)bh * SEQ;
  const int qbase = s * 64 + qh * 32;               // wave's 32 q-rows

  __shared__ __align__(16) char smem[32768];
  __half* phik_l = (__half*)smem;                   // 16 KB, single buffer
  __half* vt_l = (__half*)(smem + 16384);           // 2 x 8 KB dbuf

  const __half* pkb = phik_g + rowbase * 128;
  const __half* vtb = vt_g + (long)bh * 64 * SEQ;
  const float* ckb = ckn_g + rowbase;

  // sigma (kh-split): LDS row rho=[kh|kt|g1 g0|r1 r0] holds key [kh|g1 g0|kt|r1 r0]
  auto stageK = [&](int t) {
    const __half* ks = pkb + t * 64 * 128;
    #pragma unroll
    for (int i = 0; i < 4; ++i) {
      int seg = i * 256 + tid;
      int rho = seg >> 4;
      int sg = (rho & 32) | ((rho & 12) << 1) | ((rho & 16) >> 2) | (rho & 3);
      int off = ((seg & 15) * 8) ^ ((rho & 15) << 3);
      gll16(ks + sg * 128 + off, &phik_l[seg * 8]);
    }
  };
  auto stageV = [&](int t, int bb) {
    const __half* vs = vtb + t * 64;
    #pragma unroll
    for (int i = 0; i < 2; ++i) {
      int seg = i * 256 + tid;
      int d = seg >> 3;
      int off = ((seg & 7) * 8) ^ ((d & 7) << 3);
      gll16(vs + (long)d * SEQ + off, &vt_l[bb * 4096 + seg * 8]);
    }
  };

  stageK(0);
  stageV(0, 0);

  f16x8 bq[2][4];
  #pragma unroll
  for (int c = 0; c < 2; ++c)
    #pragma unroll
    for (int ks = 0; ks < 4; ++ks)
      bq[c][ks] = *(const f16x8*)(phiq_g + (rowbase + qbase + c * 16 + ql) * 128 + ks * 32 + g * 8);

  float lsum[2] = {0.f, 0.f};
  f32x4 acc[2][4] = {};

  for (int t = 0; t <= s; ++t) {
    const int bb = t & 1;
    asm volatile("s_waitcnt vmcnt(0)" ::: "memory");
    __builtin_amdgcn_s_barrier();
    __builtin_amdgcn_sched_barrier(0);

    // ck loads first (oldest in vmcnt FIFO)
    const float* ckt = ckb + t * 64 + kh * 32 + g * 8;
    f32x4 ckA = *(const f32x4*)(ckt);       // kt=0: keys 8g+0..3
    f32x4 ckB = *(const f32x4*)(ckt + 4);   // kt=1: keys 8g+4..7
    __builtin_amdgcn_sched_barrier(0);
    if (t < s) stageV(t + 1, bb ^ 1);       // V dbuf: full-tile latency cover
    __builtin_amdgcn_sched_barrier(0);

    const bool skip = (qbase + 31) < (t * 64 + kh * 32);

    f32x4 sS[2][2] = {};
    if (!skip) {
      __builtin_amdgcn_s_setprio(1);
      #pragma unroll
      for (int ks = 0; ks < 4; ++ks) {
        int i0 = ((kh * 32 + ql) * 128 + ks * 32 + g * 8) ^ (ql << 3);
        int i1 = ((kh * 32 + 16 + ql) * 128 + ks * 32 + g * 8) ^ (ql << 3);
        f16x8 a0 = *(const f16x8*)&phik_l[i0];
        f16x8 a1 = *(const f16x8*)&phik_l[i1];
        sS[0][0] = __builtin_amdgcn_mfma_f32_16x16x32_f16(a0, bq[0][ks], sS[0][0], 0, 0, 0);
        sS[0][1] = __builtin_amdgcn_mfma_f32_16x16x32_f16(a1, bq[0][ks], sS[0][1], 0, 0, 0);
        sS[1][0] = __builtin_amdgcn_mfma_f32_16x16x32_f16(a0, bq[1][ks], sS[1][0], 0, 0, 0);
        sS[1][1] = __builtin_amdgcn_mfma_f32_16x16x32_f16(a1, bq[1][ks], sS[1][1], 0, 0, 0);
      }
      __builtin_amdgcn_s_setprio(0);
    }

    __builtin_amdgcn_s_barrier();           // all waves done reading phik_l
    __builtin_amdgcn_sched_barrier(0);
    if (t < s) stageK(t + 1);
    __builtin_amdgcn_sched_barrier(0);

    if (!skip) {
      f16x8 pa[2];
      #pragma unroll
      for (int c = 0; c < 2; ++c) {
        const int qrow = qbase + c * 16 + ql;
        const bool domask = (t * 64 + kh * 32 + 31) > (qbase + c * 16);
        float e[8];
        #pragma unroll
        for (int kt = 0; kt < 2; ++kt)
          #pragma unroll
          for (int r = 0; r < 4; ++r) {
            float dd = sS[c][kt][r];
            float pe = fmaf(dd, dd, kt ? ckB[r] : ckA[r]);
            if (domask) {
              int key = t * 64 + kh * 32 + g * 8 + kt * 4 + r;
              pe = (key <= qrow) ? pe : 0.f;
            }
            e[kt * 4 + r] = pe;
          }
        lsum[c] += ((e[0] + e[1]) + (e[2] + e[3])) + ((e[4] + e[5]) + (e[6] + e[7]));
        U16 A;
        A.h[0] = __builtin_amdgcn_cvt_pkrtz(e[0], e[1]);
        A.h[1] = __builtin_amdgcn_cvt_pkrtz(e[2], e[3]);
        A.h[2] = __builtin_amdgcn_cvt_pkrtz(e[4], e[5]);
        A.h[3] = __builtin_amdgcn_cvt_pkrtz(e[6], e[7]);
        pa[c] = A.v;
      }

      __builtin_amdgcn_s_setprio(1);
      #pragma unroll
      for (int dt = 0; dt < 4; ++dt) {
        int idx = ((dt * 16 + ql) * 64 + kh * 32 + g * 8) ^ ((ql & 7) << 3);
        f16x8 bv = *(const f16x8*)&vt_l[bb * 4096 + idx];
        acc[0][dt] = __builtin_amdgcn_mfma_f32_16x16x32_f16(pa[0], bv, acc[0][dt], 0, 0, 0);
        acc[1][dt] = __builtin_amdgcn_mfma_f32_16x16x32_f16(pa[1], bv, acc[1][dt], 0, 0, 0);
      }
      __builtin_amdgcn_s_setprio(0);
    }
  }

  // ---- epilogue: merge kh halves (exact adds; no max state), normalize, store ----
  float* dump = (float*)smem;               // 2 x 34 x 64 floats = 17 KB
  __syncthreads();
  if (kh) {
    #pragma unroll
    for (int c = 0; c < 2; ++c) {
      #pragma unroll
      for (int dt = 0; dt < 4; ++dt)
        #pragma unroll
        for (int r = 0; r < 4; ++r)
          dump[(qh * 34 + c * 16 + dt * 4 + r) * 64 + lane] = acc[c][dt][r];
      dump[(qh * 34 + 32 + c) * 64 + lane] = lsum[c];
    }
  }
  __syncthreads();
  if (!kh) {
    #pragma unroll
    for (int c = 0; c < 2; ++c) {
      lsum[c] += dump[(qh * 34 + 32 + c) * 64 + lane];
      lsum[c] += __shfl_xor(lsum[c], 16);
      lsum[c] += __shfl_xor(lsum[c], 32);
      #pragma unroll
      for (int dt = 0; dt < 4; ++dt)
        #pragma unroll
        for (int r = 0; r < 4; ++r)
          acc[c][dt][r] += dump[(qh * 34 + c * 16 + dt * 4 + r) * 64 + lane];
    }
    #pragma unroll
    for (int c = 0; c < 2; ++c)
      #pragma unroll
      for (int r = 0; r < 4; ++r) {
        float ls = __shfl(lsum[c], (lane & 48) | (g * 4 + r));
        float inv = __builtin_amdgcn_rcpf(ls);
        float* o = out + (rowbase + qbase + c * 16 + g * 4 + r) * 64 + ql;
        #pragma unroll
        for (int dt = 0; dt < 4; ++dt) o[dt * 16] = acc[c][dt][r] * inv;
      }
  }
}

extern "C" void kernel_launch(void* const* d_in, const int* in_sizes, int n_in,
                              void* d_out, int out_size, void* d_ws, size_t ws_size,
                              hipStream_t stream) {
  const float* q = (const float*)d_in[0];
  const float* k = (const float*)d_in[1];
  const float* v = (const float*)d_in[2];
  // d_in[3] = causal mask (applied analytically)
  const float* W = (const float*)d_in[4];
  const float* b = (const float*)d_in[5];
  float* out = (float*)d_out;

  char* ws = (char*)d_ws;
  __half* phiq = (__half*)ws;                          // 16 MB
  __half* phik = (__half*)(ws + 16777216);             // 16 MB
  __half* vt = (__half*)(ws + 33554432);               // 8 MB
  float* ckn = (float*)(ws + 41943040);                // 256 KB

  prep<<<dim3(3072), 256, 0, stream>>>(q, k, v, W, b, phiq, phik, vt, ckn);
  attn_kernel<<<dim3(1024), 256, 0, stream>>>(phiq, phik, vt, ckn, out);
}

// Round 11
// 82.358 us; speedup vs baseline: 1.2900x; 1.2900x over previous
//
#include <hip/hip_runtime.h>
#include <hip/hip_fp16.h>

#define SEQ 2048
#define NBH 32
#define C1f 0.09016844005556021f   // log2(e)/16

typedef _Float16 f16x8 __attribute__((ext_vector_type(8)));
typedef __fp16 fp16x2 __attribute__((ext_vector_type(2)));
typedef float f32x4 __attribute__((ext_vector_type(4)));
typedef __attribute__((address_space(1))) const unsigned GASU;
typedef __attribute__((address_space(3))) unsigned LASU;

union U16 { fp16x2 h[4]; f16x8 v; };

__device__ __forceinline__ void gll16(const void* g, void* l) {
  __builtin_amdgcn_global_load_lds((GASU*)g, (LASU*)l, 16, 0, 0);
}

// ======== prep: projection (x<2048) + V transpose (x>=2048) ========
// phik pre-scaled by sqrt(ekn)/8 so d^2 = energy^2*ekn; ckn = 1e-5*ekn.
__global__ __launch_bounds__(256) void prep(
    const float* __restrict__ qg, const float* __restrict__ kg,
    const float* __restrict__ vg, const float* __restrict__ Wg,
    const float* __restrict__ bg,
    __half* __restrict__ phiq, __half* __restrict__ phik,
    __half* __restrict__ vt, float* __restrict__ ckn) {
  __shared__ __align__(16) float smem[64 * 68 + 64 * 64];
  const int x = blockIdx.x;
  const int tid = threadIdx.x;
  if (x >= 2048) {                       // ---- V transpose ----
    const int i = x - 2048;
    const int bh = i >> 5, s0 = (i & 31) * 64;
    float* t = smem;                     // [64][65]
    const float* base = vg + ((long)bh * SEQ + s0) * 64;
    #pragma unroll
    for (int i2 = 0; i2 < 4; ++i2) {
      int seg = i2 * 256 + tid;
      int srow = seg >> 4, sc4 = (seg & 15) << 2;
      float4 xv = *(const float4*)(base + srow * 64 + sc4);
      t[srow * 65 + sc4 + 0] = xv.x; t[srow * 65 + sc4 + 1] = xv.y;
      t[srow * 65 + sc4 + 2] = xv.z; t[srow * 65 + sc4 + 3] = xv.w;
    }
    __syncthreads();
    int d = tid >> 2, sc = (tid & 3) << 4;
    __half tmp[16];
    #pragma unroll
    for (int j = 0; j < 16; ++j) tmp[j] = __float2half(t[(sc + j) * 65 + d]);
    __half* dst = vt + ((long)bh * 64 + d) * SEQ + s0 + sc;
    *(uint4*)dst = *(uint4*)&tmp[0];
    *(uint4*)(dst + 8) = *(uint4*)&tmp[8];
    return;
  }
  // ---- projection ----
  const int wave = tid >> 6, lane = tid & 63;
  const int g = lane >> 4, ql = lane & 15;
  const int isk = x >= 1024;
  const long rowblk = (long)(x & 1023) * 64;
  const float* src = isk ? kg : qg;
  __half* dphi = isk ? phik : phiq;
  float* w_l = smem;                     // [64][68] W^T fp32
  float* x_l = smem + 64 * 68;

  #pragma unroll
  for (int i2 = 0; i2 < 4; ++i2) {       // stage W transposed
    int seg = i2 * 256 + tid;
    int d = seg >> 4, rc = (seg & 15) << 2;
    float4 wv = *(const float4*)(Wg + d * 64 + rc);
    w_l[(rc + 0) * 68 + d] = wv.x; w_l[(rc + 1) * 68 + d] = wv.y;
    w_l[(rc + 2) * 68 + d] = wv.z; w_l[(rc + 3) * 68 + d] = wv.w;
  }
  const float* xb = src + rowblk * 64;
  #pragma unroll
  for (int i2 = 0; i2 < 4; ++i2) {       // stage x (swizzled)
    int seg = i2 * 256 + tid;
    int row = seg >> 4;
    int off = ((seg & 15) * 4) ^ ((row & 7) << 2);
    gll16(xb + row * 64 + off, &x_l[seg * 4]);
  }
  float bias[4];
  #pragma unroll
  for (int rt = 0; rt < 4; ++rt) bias[rt] = bg[rt * 16 + ql];
  __syncthreads();

  f16x8 bh_[2][4], bl_[2][4];            // W hi/lo frags from LDS
  #pragma unroll
  for (int rt = 0; rt < 4; ++rt)
    #pragma unroll
    for (int ks = 0; ks < 2; ++ks) {
      f32x4 wa = *(const f32x4*)&w_l[(rt * 16 + ql) * 68 + ks * 32 + g * 8];
      f32x4 wb = *(const f32x4*)&w_l[(rt * 16 + ql) * 68 + ks * 32 + g * 8 + 4];
      #pragma unroll
      for (int j = 0; j < 4; ++j) {
        float w0 = wa[j]; _Float16 h0 = (_Float16)w0;
        bh_[ks][rt][j] = h0; bl_[ks][rt][j] = (_Float16)(w0 - (float)h0);
        float w1 = wb[j]; _Float16 h1 = (_Float16)w1;
        bh_[ks][rt][4 + j] = h1; bl_[ks][rt][4 + j] = (_Float16)(w1 - (float)h1);
      }
    }

  const int rl = wave * 16 + ql;
  float xv[16];
  #pragma unroll
  for (int ks = 0; ks < 2; ++ks)
    #pragma unroll
    for (int h = 0; h < 2; ++h) {
      int fi = (rl * 64 + ks * 32 + g * 8 + h * 4) ^ ((ql & 7) << 2);
      f32x4 u = *(const f32x4*)&x_l[fi];
      #pragma unroll
      for (int j = 0; j < 4; ++j) xv[ks * 8 + h * 4 + j] = u[j];
    }
  float nn = 0.f;
  #pragma unroll
  for (int j = 0; j < 16; ++j) nn = fmaf(xv[j], xv[j], nn);
  nn += __shfl_xor(nn, 16);
  nn += __shfl_xor(nn, 32);
  if (isk && g == 0) ckn[rowblk + rl] = 1e-5f * exp2f(nn * C1f);
  float scl = isk ? exp2f(nn * (C1f * 0.5f)) * 0.125f : 0.125f;
  float s4[4];
  #pragma unroll
  for (int i2 = 0; i2 < 4; ++i2) s4[i2] = __shfl(scl, (lane & 48) | (g * 4 + i2));

  f16x8 ah[2], al[2];
  #pragma unroll
  for (int ks = 0; ks < 2; ++ks)
    #pragma unroll
    for (int j = 0; j < 8; ++j) {
      float v = xv[ks * 8 + j];
      _Float16 hv = (_Float16)v;
      ah[ks][j] = hv;
      al[ks][j] = (_Float16)(v - (float)hv);
    }
  f32x4 sacc[4] = {};
  #pragma unroll
  for (int ks = 0; ks < 2; ++ks)
    #pragma unroll
    for (int rt = 0; rt < 4; ++rt) {
      sacc[rt] = __builtin_amdgcn_mfma_f32_16x16x32_f16(ah[ks], bh_[ks][rt], sacc[rt], 0, 0, 0);
      sacc[rt] = __builtin_amdgcn_mfma_f32_16x16x32_f16(al[ks], bh_[ks][rt], sacc[rt], 0, 0, 0);
      sacc[rt] = __builtin_amdgcn_mfma_f32_16x16x32_f16(ah[ks], bl_[ks][rt], sacc[rt], 0, 0, 0);
    }
  #pragma unroll
  for (int rt = 0; rt < 4; ++rt)
    #pragma unroll
    for (int i2 = 0; i2 < 4; ++i2) {
      float wq = sacc[rt][i2] + bias[rt];
      float sv, cv;
      __sincosf(wq, &sv, &cv);
      long row = rowblk + wave * 16 + g * 4 + i2;
      dphi[row * 128 + rt * 16 + ql] = __float2half(cv * s4[i2]);
      dphi[row * 128 + 64 + rt * 16 + ql] = __float2half(sv * s4[i2]);
    }
}

// ======== attn: 64q blocks, waves = qh x kh, balanced per-CU quads ========
__global__ __launch_bounds__(256, 3) void attn_kernel(
    const __half* __restrict__ phiq_g, const __half* __restrict__ phik_g,
    const __half* __restrict__ vt_g, const float* __restrict__ ckn_g,
    float* __restrict__ out) {
  const int x = blockIdx.x;
  // Balanced quad assignment: XCD = x&7, slot g2 = (x>>3)&31, batch = x>>8.
  // CU (XCD,g2) gets batches {31-g2, g2, 31-g2, g2} -> 66 tile-steps each.
  // Within a batch all 32 CUs of an XCD share one bh -> L2-resident phik/vt.
  const int g2 = (x >> 3) & 31;
  const int batch = x >> 8;
  const int bh = ((x & 7) << 2) | batch;
  const int s = (batch & 1) ? g2 : (31 - g2);
  const int tid = threadIdx.x;
  const int wv = tid >> 6, lane = tid & 63;
  const int g = lane >> 4, ql = lane & 15;
  const int qh = wv & 1, kh = wv >> 1;
  const long rowbase = (long)bh * SEQ;
  const int qbase = s * 64 + qh * 32;               // wave's 32 q-rows

  __shared__ __align__(16) char smem[32768];
  __half* phik_l = (__half*)smem;                   // 16 KB, single buffer
  __half* vt_l = (__half*)(smem + 16384);           // 2 x 8 KB dbuf

  const __half* pkb = phik_g + rowbase * 128;
  const __half* vtb = vt_g + (long)bh * 64 * SEQ;
  const float* ckb = ckn_g + rowbase;

  // sigma (kh-split): LDS row rho=[kh|kt|g1 g0|r1 r0] holds key [kh|g1 g0|kt|r1 r0]
  auto stageK = [&](int t) {
    const __half* ks = pkb + t * 64 * 128;
    #pragma unroll
    for (int i = 0; i < 4; ++i) {
      int seg = i * 256 + tid;
      int rho = seg >> 4;
      int sg = (rho & 32) | ((rho & 12) << 1) | ((rho & 16) >> 2) | (rho & 3);
      int off = ((seg & 15) * 8) ^ ((rho & 15) << 3);
      gll16(ks + sg * 128 + off, &phik_l[seg * 8]);
    }
  };
  auto stageV = [&](int t, int bb) {
    const __half* vs = vtb + t * 64;
    #pragma unroll
    for (int i = 0; i < 2; ++i) {
      int seg = i * 256 + tid;
      int d = seg >> 3;
      int off = ((seg & 7) * 8) ^ ((d & 7) << 3);
      gll16(vs + (long)d * SEQ + off, &vt_l[bb * 4096 + seg * 8]);
    }
  };

  stageK(0);
  stageV(0, 0);

  f16x8 bq[2][4];
  #pragma unroll
  for (int c = 0; c < 2; ++c)
    #pragma unroll
    for (int ks = 0; ks < 4; ++ks)
      bq[c][ks] = *(const f16x8*)(phiq_g + (rowbase + qbase + c * 16 + ql) * 128 + ks * 32 + g * 8);

  float lsum[2] = {0.f, 0.f};
  f32x4 acc[2][4] = {};

  for (int t = 0; t <= s; ++t) {
    const int bb = t & 1;
    asm volatile("s_waitcnt vmcnt(0)" ::: "memory");
    __builtin_amdgcn_s_barrier();
    __builtin_amdgcn_sched_barrier(0);

    // ck loads first (oldest in vmcnt FIFO)
    const float* ckt = ckb + t * 64 + kh * 32 + g * 8;
    f32x4 ckA = *(const f32x4*)(ckt);       // kt=0: keys 8g+0..3
    f32x4 ckB = *(const f32x4*)(ckt + 4);   // kt=1: keys 8g+4..7
    __builtin_amdgcn_sched_barrier(0);
    if (t < s) stageV(t + 1, bb ^ 1);       // V dbuf: full-tile latency cover
    __builtin_amdgcn_sched_barrier(0);

    const bool skip = (qbase + 31) < (t * 64 + kh * 32);

    f32x4 sS[2][2] = {};
    if (!skip) {
      __builtin_amdgcn_s_setprio(1);
      #pragma unroll
      for (int ks = 0; ks < 4; ++ks) {
        int i0 = ((kh * 32 + ql) * 128 + ks * 32 + g * 8) ^ (ql << 3);
        int i1 = ((kh * 32 + 16 + ql) * 128 + ks * 32 + g * 8) ^ (ql << 3);
        f16x8 a0 = *(const f16x8*)&phik_l[i0];
        f16x8 a1 = *(const f16x8*)&phik_l[i1];
        sS[0][0] = __builtin_amdgcn_mfma_f32_16x16x32_f16(a0, bq[0][ks], sS[0][0], 0, 0, 0);
        sS[0][1] = __builtin_amdgcn_mfma_f32_16x16x32_f16(a1, bq[0][ks], sS[0][1], 0, 0, 0);
        sS[1][0] = __builtin_amdgcn_mfma_f32_16x16x32_f16(a0, bq[1][ks], sS[1][0], 0, 0, 0);
        sS[1][1] = __builtin_amdgcn_mfma_f32_16x16x32_f16(a1, bq[1][ks], sS[1][1], 0, 0, 0);
      }
      __builtin_amdgcn_s_setprio(0);
    }

    __builtin_amdgcn_s_barrier();           // all waves done reading phik_l
    __builtin_amdgcn_sched_barrier(0);
    if (t < s) stageK(t + 1);
    __builtin_amdgcn_sched_barrier(0);

    if (!skip) {
      f16x8 pa[2];
      #pragma unroll
      for (int c = 0; c < 2; ++c) {
        const int qrow = qbase + c * 16 + ql;
        const bool domask = (t * 64 + kh * 32 + 31) > (qbase + c * 16);
        float e[8];
        #pragma unroll
        for (int kt = 0; kt < 2; ++kt)
          #pragma unroll
          for (int r = 0; r < 4; ++r) {
            float dd = sS[c][kt][r];
            float pe = fmaf(dd, dd, kt ? ckB[r] : ckA[r]);
            if (domask) {
              int key = t * 64 + kh * 32 + g * 8 + kt * 4 + r;
              pe = (key <= qrow) ? pe : 0.f;
            }
            e[kt * 4 + r] = pe;
          }
        lsum[c] += ((e[0] + e[1]) + (e[2] + e[3])) + ((e[4] + e[5]) + (e[6] + e[7]));
        U16 A;
        A.h[0] = __builtin_amdgcn_cvt_pkrtz(e[0], e[1]);
        A.h[1] = __builtin_amdgcn_cvt_pkrtz(e[2], e[3]);
        A.h[2] = __builtin_amdgcn_cvt_pkrtz(e[4], e[5]);
        A.h[3] = __builtin_amdgcn_cvt_pkrtz(e[6], e[7]);
        pa[c] = A.v;
      }

      __builtin_amdgcn_s_setprio(1);
      #pragma unroll
      for (int dt = 0; dt < 4; ++dt) {
        int idx = ((dt * 16 + ql) * 64 + kh * 32 + g * 8) ^ ((ql & 7) << 3);
        f16x8 bv = *(const f16x8*)&vt_l[bb * 4096 + idx];
        acc[0][dt] = __builtin_amdgcn_mfma_f32_16x16x32_f16(pa[0], bv, acc[0][dt], 0, 0, 0);
        acc[1][dt] = __builtin_amdgcn_mfma_f32_16x16x32_f16(pa[1], bv, acc[1][dt], 0, 0, 0);
      }
      __builtin_amdgcn_s_setprio(0);
    }
  }

  // ---- epilogue: merge kh halves (exact adds; no max state), normalize, store ----
  float* dump = (float*)smem;               // 2 x 34 x 64 floats = 17 KB
  __syncthreads();
  if (kh) {
    #pragma unroll
    for (int c = 0; c < 2; ++c) {
      #pragma unroll
      for (int dt = 0; dt < 4; ++dt)
        #pragma unroll
        for (int r = 0; r < 4; ++r)
          dump[(qh * 34 + c * 16 + dt * 4 + r) * 64 + lane] = acc[c][dt][r];
      dump[(qh * 34 + 32 + c) * 64 + lane] = lsum[c];
    }
  }
  __syncthreads();
  if (!kh) {
    #pragma unroll
    for (int c = 0; c < 2; ++c) {
      lsum[c] += dump[(qh * 34 + 32 + c) * 64 + lane];
      lsum[c] += __shfl_xor(lsum[c], 16);
      lsum[c] += __shfl_xor(lsum[c], 32);
      #pragma unroll
      for (int dt = 0; dt < 4; ++dt)
        #pragma unroll
        for (int r = 0; r < 4; ++r)
          acc[c][dt][r] += dump[(qh * 34 + c * 16 + dt * 4 + r) * 64 + lane];
    }
    #pragma unroll
    for (int c = 0; c < 2; ++c)
      #pragma unroll
      for (int r = 0; r < 4; ++r) {
        float ls = __shfl(lsum[c], (lane & 48) | (g * 4 + r));
        float inv = __builtin_amdgcn_rcpf(ls);
        float* o = out + (rowbase + qbase + c * 16 + g * 4 + r) * 64 + ql;
        #pragma unroll
        for (int dt = 0; dt < 4; ++dt) o[dt * 16] = acc[c][dt][r] * inv;
      }
  }
}

extern "C" void kernel_launch(void* const* d_in, const int* in_sizes, int n_in,
                              void* d_out, int out_size, void* d_ws, size_t ws_size,
                              hipStream_t stream) {
  const float* q = (const float*)d_in[0];
  const float* k = (const float*)d_in[1];
  const float* v = (const float*)d_in[2];
  // d_in[3] = causal mask (applied analytically)
  const float* W = (const float*)d_in[4];
  const float* b = (const float*)d_in[5];
  float* out = (float*)d_out;

  char* ws = (char*)d_ws;
  __half* phiq = (__half*)ws;                          // 16 MB
  __half* phik = (__half*)(ws + 16777216);             // 16 MB
  __half* vt = (__half*)(ws + 33554432);               // 8 MB
  float* ckn = (float*)(ws + 41943040);                // 256 KB

  prep<<<dim3(3072), 256, 0, stream>>>(q, k, v, W, b, phiq, phik, vt, ckn);
  attn_kernel<<<dim3(1024), 256, 0, stream>>>(phiq, phik, vt, ckn, out);
}

// Round 13
// 64.352 us; speedup vs baseline: 1.6509x; 1.2798x over previous
//
#include <hip/hip_runtime.h>
#include <hip/hip_fp16.h>

#define SEQ 2048
#define NBH 32
#define C1f 0.09016844005556021f   // log2(e)/16

typedef _Float16 f16x8 __attribute__((ext_vector_type(8)));
typedef __fp16 fp16x2 __attribute__((ext_vector_type(2)));
typedef float f32x4 __attribute__((ext_vector_type(4)));
typedef __attribute__((address_space(1))) const unsigned GASU;
typedef __attribute__((address_space(3))) unsigned LASU;

union U16 { fp16x2 h[4]; f16x8 v; };

__device__ __forceinline__ void gll16(const void* g, void* l) {
  __builtin_amdgcn_global_load_lds((GASU*)g, (LASU*)l, 16, 0, 0);
}

// ======== prep: projection (x<2048) + V transpose (x>=2048) ========
// phik pre-scaled by sqrt(ekn)/8 so d^2 = energy^2*ekn; ckn = 1e-5*ekn.
__global__ __launch_bounds__(256) void prep(
    const float* __restrict__ qg, const float* __restrict__ kg,
    const float* __restrict__ vg, const float* __restrict__ Wg,
    const float* __restrict__ bg,
    __half* __restrict__ phiq, __half* __restrict__ phik,
    __half* __restrict__ vt, float* __restrict__ ckn) {
  __shared__ __align__(16) float smem[64 * 68 + 64 * 64];
  const int x = blockIdx.x;
  const int tid = threadIdx.x;
  if (x >= 2048) {                       // ---- V transpose ----
    const int i = x - 2048;
    const int bh = i >> 5, s0 = (i & 31) * 64;
    float* t = smem;                     // [64][65]
    const float* base = vg + ((long)bh * SEQ + s0) * 64;
    #pragma unroll
    for (int i2 = 0; i2 < 4; ++i2) {
      int seg = i2 * 256 + tid;
      int srow = seg >> 4, sc4 = (seg & 15) << 2;
      float4 xv = *(const float4*)(base + srow * 64 + sc4);
      t[srow * 65 + sc4 + 0] = xv.x; t[srow * 65 + sc4 + 1] = xv.y;
      t[srow * 65 + sc4 + 2] = xv.z; t[srow * 65 + sc4 + 3] = xv.w;
    }
    __syncthreads();
    int d = tid >> 2, sc = (tid & 3) << 4;
    __half tmp[16];
    #pragma unroll
    for (int j = 0; j < 16; ++j) tmp[j] = __float2half(t[(sc + j) * 65 + d]);
    __half* dst = vt + ((long)bh * 64 + d) * SEQ + s0 + sc;
    *(uint4*)dst = *(uint4*)&tmp[0];
    *(uint4*)(dst + 8) = *(uint4*)&tmp[8];
    return;
  }
  // ---- projection ----
  const int wave = tid >> 6, lane = tid & 63;
  const int g = lane >> 4, ql = lane & 15;
  const int isk = x >= 1024;
  const long rowblk = (long)(x & 1023) * 64;
  const float* src = isk ? kg : qg;
  __half* dphi = isk ? phik : phiq;
  float* w_l = smem;                     // [64][68] W^T fp32
  float* x_l = smem + 64 * 68;

  #pragma unroll
  for (int i2 = 0; i2 < 4; ++i2) {       // stage W transposed
    int seg = i2 * 256 + tid;
    int d = seg >> 4, rc = (seg & 15) << 2;
    float4 wv = *(const float4*)(Wg + d * 64 + rc);
    w_l[(rc + 0) * 68 + d] = wv.x; w_l[(rc + 1) * 68 + d] = wv.y;
    w_l[(rc + 2) * 68 + d] = wv.z; w_l[(rc + 3) * 68 + d] = wv.w;
  }
  const float* xb = src + rowblk * 64;
  #pragma unroll
  for (int i2 = 0; i2 < 4; ++i2) {       // stage x (swizzled)
    int seg = i2 * 256 + tid;
    int row = seg >> 4;
    int off = ((seg & 15) * 4) ^ ((row & 7) << 2);
    gll16(xb + row * 64 + off, &x_l[seg * 4]);
  }
  float bias[4];
  #pragma unroll
  for (int rt = 0; rt < 4; ++rt) bias[rt] = bg[rt * 16 + ql];
  __syncthreads();

  f16x8 bh_[2][4], bl_[2][4];            // W hi/lo frags from LDS
  #pragma unroll
  for (int rt = 0; rt < 4; ++rt)
    #pragma unroll
    for (int ks = 0; ks < 2; ++ks) {
      f32x4 wa = *(const f32x4*)&w_l[(rt * 16 + ql) * 68 + ks * 32 + g * 8];
      f32x4 wb = *(const f32x4*)&w_l[(rt * 16 + ql) * 68 + ks * 32 + g * 8 + 4];
      #pragma unroll
      for (int j = 0; j < 4; ++j) {
        float w0 = wa[j]; _Float16 h0 = (_Float16)w0;
        bh_[ks][rt][j] = h0; bl_[ks][rt][j] = (_Float16)(w0 - (float)h0);
        float w1 = wb[j]; _Float16 h1 = (_Float16)w1;
        bh_[ks][rt][4 + j] = h1; bl_[ks][rt][4 + j] = (_Float16)(w1 - (float)h1);
      }
    }

  const int rl = wave * 16 + ql;
  float xv[16];
  #pragma unroll
  for (int ks = 0; ks < 2; ++ks)
    #pragma unroll
    for (int h = 0; h < 2; ++h) {
      int fi = (rl * 64 + ks * 32 + g * 8 + h * 4) ^ ((ql & 7) << 2);
      f32x4 u = *(const f32x4*)&x_l[fi];
      #pragma unroll
      for (int j = 0; j < 4; ++j) xv[ks * 8 + h * 4 + j] = u[j];
    }
  float nn = 0.f;
  #pragma unroll
  for (int j = 0; j < 16; ++j) nn = fmaf(xv[j], xv[j], nn);
  nn += __shfl_xor(nn, 16);
  nn += __shfl_xor(nn, 32);
  if (isk && g == 0) ckn[rowblk + rl] = 1e-5f * exp2f(nn * C1f);
  float scl = isk ? exp2f(nn * (C1f * 0.5f)) * 0.125f : 0.125f;
  float s4[4];
  #pragma unroll
  for (int i2 = 0; i2 < 4; ++i2) s4[i2] = __shfl(scl, (lane & 48) | (g * 4 + i2));

  f16x8 ah[2], al[2];
  #pragma unroll
  for (int ks = 0; ks < 2; ++ks)
    #pragma unroll
    for (int j = 0; j < 8; ++j) {
      float v = xv[ks * 8 + j];
      _Float16 hv = (_Float16)v;
      ah[ks][j] = hv;
      al[ks][j] = (_Float16)(v - (float)hv);
    }
  f32x4 sacc[4] = {};
  #pragma unroll
  for (int ks = 0; ks < 2; ++ks)
    #pragma unroll
    for (int rt = 0; rt < 4; ++rt) {
      sacc[rt] = __builtin_amdgcn_mfma_f32_16x16x32_f16(ah[ks], bh_[ks][rt], sacc[rt], 0, 0, 0);
      sacc[rt] = __builtin_amdgcn_mfma_f32_16x16x32_f16(al[ks], bh_[ks][rt], sacc[rt], 0, 0, 0);
      sacc[rt] = __builtin_amdgcn_mfma_f32_16x16x32_f16(ah[ks], bl_[ks][rt], sacc[rt], 0, 0, 0);
    }
  #pragma unroll
  for (int rt = 0; rt < 4; ++rt)
    #pragma unroll
    for (int i2 = 0; i2 < 4; ++i2) {
      float wq = sacc[rt][i2] + bias[rt];
      float sv, cv;
      __sincosf(wq, &sv, &cv);
      long row = rowblk + wave * 16 + g * 4 + i2;
      dphi[row * 128 + rt * 16 + ql] = __float2half(cv * s4[i2]);
      dphi[row * 128 + 64 + rt * 16 + ql] = __float2half(sv * s4[i2]);
    }
}

// ======== attn: 64q blocks (r9 mapping), K+V double-buffered, ONE barrier/step ========
__global__ __launch_bounds__(256, 3) void attn_kernel(
    const __half* __restrict__ phiq_g, const __half* __restrict__ phik_g,
    const __half* __restrict__ vt_g, const float* __restrict__ ckn_g,
    float* __restrict__ out) {
  const int x = blockIdx.x;
  const int bh = ((x & 7) << 2) | ((x >> 3) & 3);   // XCD-packed bh (r9, proven)
  const int s = 31 - (x >> 5);                      // heavy strips first
  const int tid = threadIdx.x;
  const int wv = tid >> 6, lane = tid & 63;
  const int g = lane >> 4, ql = lane & 15;
  const int qh = wv & 1, kh = wv >> 1;
  const long rowbase = (long)bh * SEQ;
  const int qbase = s * 64 + qh * 32;               // wave's 32 q-rows

  __shared__ __align__(16) char smem[49152];
  __half* phik_l = (__half*)smem;                   // 2 x 16 KB dbuf (8192 halves each)
  __half* vt_l = (__half*)(smem + 32768);           // 2 x 8 KB dbuf (4096 halves each)

  const __half* pkb = phik_g + rowbase * 128;
  const __half* vtb = vt_g + (long)bh * 64 * SEQ;
  const float* ckb = ckn_g + rowbase;

  // sigma (kh-split): LDS row rho=[kh|kt|g1 g0|r1 r0] holds key [kh|g1 g0|kt|r1 r0]
  auto stageK = [&](int t, int bb) {
    const __half* ks = pkb + t * 64 * 128;
    #pragma unroll
    for (int i = 0; i < 4; ++i) {
      int seg = i * 256 + tid;
      int rho = seg >> 4;
      int sg = (rho & 32) | ((rho & 12) << 1) | ((rho & 16) >> 2) | (rho & 3);
      int off = ((seg & 15) * 8) ^ ((rho & 15) << 3);
      gll16(ks + sg * 128 + off, &phik_l[bb * 8192 + seg * 8]);
    }
  };
  auto stageV = [&](int t, int bb) {
    const __half* vs = vtb + t * 64;
    #pragma unroll
    for (int i = 0; i < 2; ++i) {
      int seg = i * 256 + tid;
      int d = seg >> 3;
      int off = ((seg & 7) * 8) ^ ((d & 7) << 3);
      gll16(vs + (long)d * SEQ + off, &vt_l[bb * 4096 + seg * 8]);
    }
  };

  stageK(0, 0);
  stageV(0, 0);

  f16x8 bq[2][4];
  #pragma unroll
  for (int c = 0; c < 2; ++c)
    #pragma unroll
    for (int ks = 0; ks < 4; ++ks)
      bq[c][ks] = *(const f16x8*)(phiq_g + (rowbase + qbase + c * 16 + ql) * 128 + ks * 32 + g * 8);

  float lsum[2] = {0.f, 0.f};
  f32x4 acc[2][4] = {};

  for (int t = 0; t <= s; ++t) {
    const int bb = t & 1;
    // One barrier per step: stage(t) into bb completed (own vmcnt drained by each
    // wave, then barrier); barrier also means all waves are done READING bb^1
    // (step t-1), so we can immediately re-stage bb^1 for t+1 with a full step
    // of latency cover.
    asm volatile("s_waitcnt vmcnt(0)" ::: "memory");
    __builtin_amdgcn_s_barrier();
    __builtin_amdgcn_sched_barrier(0);

    // ck loads first (oldest in vmcnt FIFO -> their wait leaves staging in flight)
    const float* ckt = ckb + t * 64 + kh * 32 + g * 8;
    f32x4 ckA = *(const f32x4*)(ckt);       // kt=0: keys 8g+0..3
    f32x4 ckB = *(const f32x4*)(ckt + 4);   // kt=1: keys 8g+4..7
    __builtin_amdgcn_sched_barrier(0);
    if (t < s) { stageK(t + 1, bb ^ 1); stageV(t + 1, bb ^ 1); }
    __builtin_amdgcn_sched_barrier(0);

    const bool skip = (qbase + 31) < (t * 64 + kh * 32);
    if (!skip) {
      f32x4 sS[2][2] = {};
      __builtin_amdgcn_s_setprio(1);
      #pragma unroll
      for (int ks = 0; ks < 4; ++ks) {
        int i0 = (bb * 8192 + (kh * 32 + ql) * 128 + ks * 32 + g * 8) ^ (ql << 3);
        int i1 = (bb * 8192 + (kh * 32 + 16 + ql) * 128 + ks * 32 + g * 8) ^ (ql << 3);
        f16x8 a0 = *(const f16x8*)&phik_l[i0];
        f16x8 a1 = *(const f16x8*)&phik_l[i1];
        sS[0][0] = __builtin_amdgcn_mfma_f32_16x16x32_f16(a0, bq[0][ks], sS[0][0], 0, 0, 0);
        sS[0][1] = __builtin_amdgcn_mfma_f32_16x16x32_f16(a1, bq[0][ks], sS[0][1], 0, 0, 0);
        sS[1][0] = __builtin_amdgcn_mfma_f32_16x16x32_f16(a0, bq[1][ks], sS[1][0], 0, 0, 0);
        sS[1][1] = __builtin_amdgcn_mfma_f32_16x16x32_f16(a1, bq[1][ks], sS[1][1], 0, 0, 0);
      }
      __builtin_amdgcn_s_setprio(0);

      f16x8 pa[2];
      #pragma unroll
      for (int c = 0; c < 2; ++c) {
        const int qrow = qbase + c * 16 + ql;
        const bool domask = (t * 64 + kh * 32 + 31) > (qbase + c * 16);
        float e[8];
        #pragma unroll
        for (int kt = 0; kt < 2; ++kt)
          #pragma unroll
          for (int r = 0; r < 4; ++r) {
            float dd = sS[c][kt][r];
            float pe = fmaf(dd, dd, kt ? ckB[r] : ckA[r]);
            if (domask) {
              int key = t * 64 + kh * 32 + g * 8 + kt * 4 + r;
              pe = (key <= qrow) ? pe : 0.f;
            }
            e[kt * 4 + r] = pe;
          }
        lsum[c] += ((e[0] + e[1]) + (e[2] + e[3])) + ((e[4] + e[5]) + (e[6] + e[7]));
        U16 A;
        A.h[0] = __builtin_amdgcn_cvt_pkrtz(e[0], e[1]);
        A.h[1] = __builtin_amdgcn_cvt_pkrtz(e[2], e[3]);
        A.h[2] = __builtin_amdgcn_cvt_pkrtz(e[4], e[5]);
        A.h[3] = __builtin_amdgcn_cvt_pkrtz(e[6], e[7]);
        pa[c] = A.v;
      }

      __builtin_amdgcn_s_setprio(1);
      #pragma unroll
      for (int dt = 0; dt < 4; ++dt) {
        int idx = (bb * 4096 + (dt * 16 + ql) * 64 + kh * 32 + g * 8) ^ ((ql & 7) << 3);
        f16x8 bv = *(const f16x8*)&vt_l[idx];
        acc[0][dt] = __builtin_amdgcn_mfma_f32_16x16x32_f16(pa[0], bv, acc[0][dt], 0, 0, 0);
        acc[1][dt] = __builtin_amdgcn_mfma_f32_16x16x32_f16(pa[1], bv, acc[1][dt], 0, 0, 0);
      }
      __builtin_amdgcn_s_setprio(0);
    }
  }

  // ---- epilogue: merge kh halves (exact adds; no max state), normalize, store ----
  float* dump = (float*)smem;               // 2 x 34 x 64 floats = 17 KB
  __syncthreads();
  if (kh) {
    #pragma unroll
    for (int c = 0; c < 2; ++c) {
      #pragma unroll
      for (int dt = 0; dt < 4; ++dt)
        #pragma unroll
        for (int r = 0; r < 4; ++r)
          dump[(qh * 34 + c * 16 + dt * 4 + r) * 64 + lane] = acc[c][dt][r];
      dump[(qh * 34 + 32 + c) * 64 + lane] = lsum[c];
    }
  }
  __syncthreads();
  if (!kh) {
    #pragma unroll
    for (int c = 0; c < 2; ++c) {
      lsum[c] += dump[(qh * 34 + 32 + c) * 64 + lane];
      lsum[c] += __shfl_xor(lsum[c], 16);
      lsum[c] += __shfl_xor(lsum[c], 32);
      #pragma unroll
      for (int dt = 0; dt < 4; ++dt)
        #pragma unroll
        for (int r = 0; r < 4; ++r)
          acc[c][dt][r] += dump[(qh * 34 + c * 16 + dt * 4 + r) * 64 + lane];
    }
    #pragma unroll
    for (int c = 0; c < 2; ++c)
      #pragma unroll
      for (int r = 0; r < 4; ++r) {
        float ls = __shfl(lsum[c], (lane & 48) | (g * 4 + r));
        float inv = __builtin_amdgcn_rcpf(ls);
        float* o = out + (rowbase + qbase + c * 16 + g * 4 + r) * 64 + ql;
        #pragma unroll
        for (int dt = 0; dt < 4; ++dt) o[dt * 16] = acc[c][dt][r] * inv;
      }
  }
}

extern "C" void kernel_launch(void* const* d_in, const int* in_sizes, int n_in,
                              void* d_out, int out_size, void* d_ws, size_t ws_size,
                              hipStream_t stream) {
  const float* q = (const float*)d_in[0];
  const float* k = (const float*)d_in[1];
  const float* v = (const float*)d_in[2];
  // d_in[3] = causal mask (applied analytically)
  const float* W = (const float*)d_in[4];
  const float* b = (const float*)d_in[5];
  float* out = (float*)d_out;

  char* ws = (char*)d_ws;
  __half* phiq = (__half*)ws;                          // 16 MB
  __half* phik = (__half*)(ws + 16777216);             // 16 MB
  __half* vt = (__half*)(ws + 33554432);               // 8 MB
  float* ckn = (float*)(ws + 41943040);                // 256 KB

  prep<<<dim3(3072), 256, 0, stream>>>(q, k, v, W, b, phiq, phik, vt, ckn);
  attn_kernel<<<dim3(1024), 256, 0, stream>>>(phiq, phik, vt, ckn, out);
}

// Round 14
// 61.778 us; speedup vs baseline: 1.7197x; 1.0417x over previous
//
#include <hip/hip_runtime.h>
#include <hip/hip_fp16.h>

#define SEQ 2048
#define NBH 32
#define C1f 0.09016844005556021f   // log2(e)/16

typedef _Float16 f16x8 __attribute__((ext_vector_type(8)));
typedef __fp16 fp16x2 __attribute__((ext_vector_type(2)));
typedef float f32x4 __attribute__((ext_vector_type(4)));
typedef __attribute__((address_space(1))) const unsigned GASU;
typedef __attribute__((address_space(3))) unsigned LASU;

union U16 { fp16x2 h[4]; f16x8 v; };

__device__ __forceinline__ void gll16(const void* g, void* l) {
  __builtin_amdgcn_global_load_lds((GASU*)g, (LASU*)l, 16, 0, 0);
}

// ======== prep: projection (x<2048) + V transpose (x>=2048) ========
// phik pre-scaled by sqrt(ekn)/8 so d^2 = energy^2*ekn; ckn = 1e-5*ekn.
__global__ __launch_bounds__(256) void prep(
    const float* __restrict__ qg, const float* __restrict__ kg,
    const float* __restrict__ vg, const float* __restrict__ Wg,
    const float* __restrict__ bg,
    __half* __restrict__ phiq, __half* __restrict__ phik,
    __half* __restrict__ vt, float* __restrict__ ckn) {
  __shared__ __align__(16) float smem[64 * 68 + 64 * 64];
  const int x = blockIdx.x;
  const int tid = threadIdx.x;
  if (x >= 2048) {                       // ---- V transpose ----
    const int i = x - 2048;
    const int bh = i >> 5, s0 = (i & 31) * 64;
    float* t = smem;                     // [64][65]
    const float* base = vg + ((long)bh * SEQ + s0) * 64;
    #pragma unroll
    for (int i2 = 0; i2 < 4; ++i2) {
      int seg = i2 * 256 + tid;
      int srow = seg >> 4, sc4 = (seg & 15) << 2;
      float4 xv = *(const float4*)(base + srow * 64 + sc4);
      t[srow * 65 + sc4 + 0] = xv.x; t[srow * 65 + sc4 + 1] = xv.y;
      t[srow * 65 + sc4 + 2] = xv.z; t[srow * 65 + sc4 + 3] = xv.w;
    }
    __syncthreads();
    int d = tid >> 2, sc = (tid & 3) << 4;
    __half tmp[16];
    #pragma unroll
    for (int j = 0; j < 16; ++j) tmp[j] = __float2half(t[(sc + j) * 65 + d]);
    __half* dst = vt + ((long)bh * 64 + d) * SEQ + s0 + sc;
    *(uint4*)dst = *(uint4*)&tmp[0];
    *(uint4*)(dst + 8) = *(uint4*)&tmp[8];
    return;
  }
  // ---- projection ----
  const int wave = tid >> 6, lane = tid & 63;
  const int g = lane >> 4, ql = lane & 15;
  const int isk = x >= 1024;
  const long rowblk = (long)(x & 1023) * 64;
  const float* src = isk ? kg : qg;
  __half* dphi = isk ? phik : phiq;
  float* w_l = smem;                     // [64][68] W^T fp32
  float* x_l = smem + 64 * 68;

  #pragma unroll
  for (int i2 = 0; i2 < 4; ++i2) {       // stage W transposed
    int seg = i2 * 256 + tid;
    int d = seg >> 4, rc = (seg & 15) << 2;
    float4 wv = *(const float4*)(Wg + d * 64 + rc);
    w_l[(rc + 0) * 68 + d] = wv.x; w_l[(rc + 1) * 68 + d] = wv.y;
    w_l[(rc + 2) * 68 + d] = wv.z; w_l[(rc + 3) * 68 + d] = wv.w;
  }
  const float* xb = src + rowblk * 64;
  #pragma unroll
  for (int i2 = 0; i2 < 4; ++i2) {       // stage x (swizzled)
    int seg = i2 * 256 + tid;
    int row = seg >> 4;
    int off = ((seg & 15) * 4) ^ ((row & 7) << 2);
    gll16(xb + row * 64 + off, &x_l[seg * 4]);
  }
  float bias[4];
  #pragma unroll
  for (int rt = 0; rt < 4; ++rt) bias[rt] = bg[rt * 16 + ql];
  __syncthreads();

  f16x8 bh_[2][4], bl_[2][4];            // W hi/lo frags from LDS
  #pragma unroll
  for (int rt = 0; rt < 4; ++rt)
    #pragma unroll
    for (int ks = 0; ks < 2; ++ks) {
      f32x4 wa = *(const f32x4*)&w_l[(rt * 16 + ql) * 68 + ks * 32 + g * 8];
      f32x4 wb = *(const f32x4*)&w_l[(rt * 16 + ql) * 68 + ks * 32 + g * 8 + 4];
      #pragma unroll
      for (int j = 0; j < 4; ++j) {
        float w0 = wa[j]; _Float16 h0 = (_Float16)w0;
        bh_[ks][rt][j] = h0; bl_[ks][rt][j] = (_Float16)(w0 - (float)h0);
        float w1 = wb[j]; _Float16 h1 = (_Float16)w1;
        bh_[ks][rt][4 + j] = h1; bl_[ks][rt][4 + j] = (_Float16)(w1 - (float)h1);
      }
    }

  const int rl = wave * 16 + ql;
  float xv[16];
  #pragma unroll
  for (int ks = 0; ks < 2; ++ks)
    #pragma unroll
    for (int h = 0; h < 2; ++h) {
      int fi = (rl * 64 + ks * 32 + g * 8 + h * 4) ^ ((ql & 7) << 2);
      f32x4 u = *(const f32x4*)&x_l[fi];
      #pragma unroll
      for (int j = 0; j < 4; ++j) xv[ks * 8 + h * 4 + j] = u[j];
    }
  float nn = 0.f;
  #pragma unroll
  for (int j = 0; j < 16; ++j) nn = fmaf(xv[j], xv[j], nn);
  nn += __shfl_xor(nn, 16);
  nn += __shfl_xor(nn, 32);
  if (isk && g == 0) ckn[rowblk + rl] = 1e-5f * exp2f(nn * C1f);
  float scl = isk ? exp2f(nn * (C1f * 0.5f)) * 0.125f : 0.125f;
  float s4[4];
  #pragma unroll
  for (int i2 = 0; i2 < 4; ++i2) s4[i2] = __shfl(scl, (lane & 48) | (g * 4 + i2));

  f16x8 ah[2], al[2];
  #pragma unroll
  for (int ks = 0; ks < 2; ++ks)
    #pragma unroll
    for (int j = 0; j < 8; ++j) {
      float v = xv[ks * 8 + j];
      _Float16 hv = (_Float16)v;
      ah[ks][j] = hv;
      al[ks][j] = (_Float16)(v - (float)hv);
    }
  f32x4 sacc[4] = {};
  #pragma unroll
  for (int ks = 0; ks < 2; ++ks)
    #pragma unroll
    for (int rt = 0; rt < 4; ++rt) {
      sacc[rt] = __builtin_amdgcn_mfma_f32_16x16x32_f16(ah[ks], bh_[ks][rt], sacc[rt], 0, 0, 0);
      sacc[rt] = __builtin_amdgcn_mfma_f32_16x16x32_f16(al[ks], bh_[ks][rt], sacc[rt], 0, 0, 0);
      sacc[rt] = __builtin_amdgcn_mfma_f32_16x16x32_f16(ah[ks], bl_[ks][rt], sacc[rt], 0, 0, 0);
    }
  #pragma unroll
  for (int rt = 0; rt < 4; ++rt)
    #pragma unroll
    for (int i2 = 0; i2 < 4; ++i2) {
      float wq = sacc[rt][i2] + bias[rt];
      float sv, cv;
      __sincosf(wq, &sv, &cv);
      long row = rowblk + wave * 16 + g * 4 + i2;
      dphi[row * 128 + rt * 16 + ql] = __float2half(cv * s4[i2]);
      dphi[row * 128 + 64 + rt * 16 + ql] = __float2half(sv * s4[i2]);
    }
}

// ======== attn: r13 schedule + precomputed offsets + 2x unroll (static bb) ========
__global__ __launch_bounds__(256, 3) void attn_kernel(
    const __half* __restrict__ phiq_g, const __half* __restrict__ phik_g,
    const __half* __restrict__ vt_g, const float* __restrict__ ckn_g,
    float* __restrict__ out) {
  const int x = blockIdx.x;
  const int bh = ((x & 7) << 2) | ((x >> 3) & 3);   // XCD-packed bh
  const int s = 31 - (x >> 5);                      // heavy strips first
  const int tid = threadIdx.x;
  const int wv = tid >> 6, lane = tid & 63;
  const int g = lane >> 4, ql = lane & 15;
  const int qh = wv & 1, kh = wv >> 1;
  const long rowbase = (long)bh * SEQ;
  const int qbase = s * 64 + qh * 32;               // wave's 32 q-rows

  __shared__ __align__(16) char smem[49152];
  __half* phik_l = (__half*)smem;                   // 2 x 8192 halves
  __half* vt_l = (__half*)(smem + 32768);           // 2 x 4096 halves

  const __half* pkb = phik_g + rowbase * 128;
  const __half* vtb = vt_g + (long)bh * 64 * SEQ;
  const float* ckp = ckn_g + rowbase + kh * 32 + g * 8;

  // ---- precomputed per-lane staging offsets (constant across all steps) ----
  // sigma (kh-split): LDS row rho=[kh|kt|g1 g0|r1 r0] holds key [kh|g1 g0|kt|r1 r0]
  unsigned koffv[4], kdstv[4], voffv[2], vdstv[2];
  #pragma unroll
  for (int i = 0; i < 4; ++i) {
    int seg = i * 256 + tid;
    int rho = seg >> 4;
    int sg = (rho & 32) | ((rho & 12) << 1) | ((rho & 16) >> 2) | (rho & 3);
    int off = ((seg & 15) * 8) ^ ((rho & 15) << 3);
    koffv[i] = sg * 128 + off;
    kdstv[i] = seg * 8;
  }
  #pragma unroll
  for (int i = 0; i < 2; ++i) {
    int seg = i * 256 + tid;
    int d = seg >> 3;
    int off = ((seg & 7) * 8) ^ ((d & 7) << 3);
    voffv[i] = d * SEQ + off;
    vdstv[i] = seg * 8;
  }

  // bb is always a literal at call sites -> static LDS offsets after inlining
  auto stageKV = [&](int tn, int bb) {
    const __half* kb = pkb + (long)tn * 8192;
    #pragma unroll
    for (int i = 0; i < 4; ++i) gll16(kb + koffv[i], phik_l + bb * 8192 + kdstv[i]);
    const __half* vb = vtb + tn * 64;
    #pragma unroll
    for (int i = 0; i < 2; ++i) gll16(vb + voffv[i], vt_l + bb * 4096 + vdstv[i]);
  };

  stageKV(0, 0);

  f16x8 bq[2][4];
  #pragma unroll
  for (int c = 0; c < 2; ++c)
    #pragma unroll
    for (int ks = 0; ks < 4; ++ks)
      bq[c][ks] = *(const f16x8*)(phiq_g + (rowbase + qbase + c * 16 + ql) * 128 + ks * 32 + g * 8);

  float lsum[2] = {0.f, 0.f};
  f32x4 acc[2][4] = {};

  auto step = [&](int t, int bb) {
    // One barrier per step: stage(t)->bb complete; all waves done reading bb^1.
    asm volatile("s_waitcnt vmcnt(0)" ::: "memory");
    __builtin_amdgcn_s_barrier();
    __builtin_amdgcn_sched_barrier(0);

    // ck loads first (oldest in vmcnt FIFO -> their wait leaves staging in flight)
    const float* ckt = ckp + t * 64;
    f32x4 ckA = *(const f32x4*)(ckt);
    f32x4 ckB = *(const f32x4*)(ckt + 4);
    __builtin_amdgcn_sched_barrier(0);
    if (t < s) stageKV(t + 1, bb ^ 1);
    __builtin_amdgcn_sched_barrier(0);

    const bool skip = (qbase + 31) < (t * 64 + kh * 32);
    if (!skip) {
      f32x4 sS[2][2] = {};
      __builtin_amdgcn_s_setprio(1);
      #pragma unroll
      for (int ks = 0; ks < 4; ++ks) {
        int i0 = (bb * 8192 + (kh * 32 + ql) * 128 + ks * 32 + g * 8) ^ (ql << 3);
        int i1 = (bb * 8192 + (kh * 32 + 16 + ql) * 128 + ks * 32 + g * 8) ^ (ql << 3);
        f16x8 a0 = *(const f16x8*)&phik_l[i0];
        f16x8 a1 = *(const f16x8*)&phik_l[i1];
        sS[0][0] = __builtin_amdgcn_mfma_f32_16x16x32_f16(a0, bq[0][ks], sS[0][0], 0, 0, 0);
        sS[0][1] = __builtin_amdgcn_mfma_f32_16x16x32_f16(a1, bq[0][ks], sS[0][1], 0, 0, 0);
        sS[1][0] = __builtin_amdgcn_mfma_f32_16x16x32_f16(a0, bq[1][ks], sS[1][0], 0, 0, 0);
        sS[1][1] = __builtin_amdgcn_mfma_f32_16x16x32_f16(a1, bq[1][ks], sS[1][1], 0, 0, 0);
      }
      __builtin_amdgcn_s_setprio(0);

      f16x8 pa[2];
      #pragma unroll
      for (int c = 0; c < 2; ++c) {
        const int qrow = qbase + c * 16 + ql;
        const bool domask = (t * 64 + kh * 32 + 31) > (qbase + c * 16);
        float e[8];
        #pragma unroll
        for (int kt = 0; kt < 2; ++kt)
          #pragma unroll
          for (int r = 0; r < 4; ++r) {
            float dd = sS[c][kt][r];
            float pe = fmaf(dd, dd, kt ? ckB[r] : ckA[r]);
            if (domask) {
              int key = t * 64 + kh * 32 + g * 8 + kt * 4 + r;
              pe = (key <= qrow) ? pe : 0.f;
            }
            e[kt * 4 + r] = pe;
          }
        lsum[c] += ((e[0] + e[1]) + (e[2] + e[3])) + ((e[4] + e[5]) + (e[6] + e[7]));
        U16 A;
        A.h[0] = __builtin_amdgcn_cvt_pkrtz(e[0], e[1]);
        A.h[1] = __builtin_amdgcn_cvt_pkrtz(e[2], e[3]);
        A.h[2] = __builtin_amdgcn_cvt_pkrtz(e[4], e[5]);
        A.h[3] = __builtin_amdgcn_cvt_pkrtz(e[6], e[7]);
        pa[c] = A.v;
      }

      __builtin_amdgcn_s_setprio(1);
      #pragma unroll
      for (int dt = 0; dt < 4; ++dt) {
        int idx = (bb * 4096 + (dt * 16 + ql) * 64 + kh * 32 + g * 8) ^ ((ql & 7) << 3);
        f16x8 bv = *(const f16x8*)&vt_l[idx];
        acc[0][dt] = __builtin_amdgcn_mfma_f32_16x16x32_f16(pa[0], bv, acc[0][dt], 0, 0, 0);
        acc[1][dt] = __builtin_amdgcn_mfma_f32_16x16x32_f16(pa[1], bv, acc[1][dt], 0, 0, 0);
      }
      __builtin_amdgcn_s_setprio(0);
    }
  };

  for (int t = 0; t <= s; t += 2) {
    step(t, 0);                          // inlined with literal bb=0
    if (t + 1 <= s) step(t + 1, 1);      // inlined with literal bb=1
  }

  // ---- epilogue: merge kh halves (exact adds; no max state), normalize, store ----
  float* dump = (float*)smem;               // 2 x 34 x 64 floats = 17 KB
  __syncthreads();
  if (kh) {
    #pragma unroll
    for (int c = 0; c < 2; ++c) {
      #pragma unroll
      for (int dt = 0; dt < 4; ++dt)
        #pragma unroll
        for (int r = 0; r < 4; ++r)
          dump[(qh * 34 + c * 16 + dt * 4 + r) * 64 + lane] = acc[c][dt][r];
      dump[(qh * 34 + 32 + c) * 64 + lane] = lsum[c];
    }
  }
  __syncthreads();
  if (!kh) {
    #pragma unroll
    for (int c = 0; c < 2; ++c) {
      lsum[c] += dump[(qh * 34 + 32 + c) * 64 + lane];
      lsum[c] += __shfl_xor(lsum[c], 16);
      lsum[c] += __shfl_xor(lsum[c], 32);
      #pragma unroll
      for (int dt = 0; dt < 4; ++dt)
        #pragma unroll
        for (int r = 0; r < 4; ++r)
          acc[c][dt][r] += dump[(qh * 34 + c * 16 + dt * 4 + r) * 64 + lane];
    }
    #pragma unroll
    for (int c = 0; c < 2; ++c)
      #pragma unroll
      for (int r = 0; r < 4; ++r) {
        float ls = __shfl(lsum[c], (lane & 48) | (g * 4 + r));
        float inv = __builtin_amdgcn_rcpf(ls);
        float* o = out + (rowbase + qbase + c * 16 + g * 4 + r) * 64 + ql;
        #pragma unroll
        for (int dt = 0; dt < 4; ++dt) o[dt * 16] = acc[c][dt][r] * inv;
      }
  }
}

extern "C" void kernel_launch(void* const* d_in, const int* in_sizes, int n_in,
                              void* d_out, int out_size, void* d_ws, size_t ws_size,
                              hipStream_t stream) {
  const float* q = (const float*)d_in[0];
  const float* k = (const float*)d_in[1];
  const float* v = (const float*)d_in[2];
  // d_in[3] = causal mask (applied analytically)
  const float* W = (const float*)d_in[4];
  const float* b = (const float*)d_in[5];
  float* out = (float*)d_out;

  char* ws = (char*)d_ws;
  __half* phiq = (__half*)ws;                          // 16 MB
  __half* phik = (__half*)(ws + 16777216);             // 16 MB
  __half* vt = (__half*)(ws + 33554432);               // 8 MB
  float* ckn = (float*)(ws + 41943040);                // 256 KB

  prep<<<dim3(3072), 256, 0, stream>>>(q, k, v, W, b, phiq, phik, vt, ckn);
  attn_kernel<<<dim3(1024), 256, 0, stream>>>(phiq, phik, vt, ckn, out);
}

// Round 15
// 61.285 us; speedup vs baseline: 1.7336x; 1.0081x over previous
//
#include <hip/hip_runtime.h>
#include <hip/hip_fp16.h>

#define SEQ 2048
#define NBH 32
#define C1f 0.09016844005556021f   // log2(e)/16

typedef _Float16 f16x8 __attribute__((ext_vector_type(8)));
typedef __fp16 fp16x2 __attribute__((ext_vector_type(2)));
typedef float f32x4 __attribute__((ext_vector_type(4)));
typedef __attribute__((address_space(1))) const unsigned GASU;
typedef __attribute__((address_space(3))) unsigned LASU;

union U16 { fp16x2 h[4]; f16x8 v; };

__device__ __forceinline__ void gll16(const void* g, void* l) {
  __builtin_amdgcn_global_load_lds((GASU*)g, (LASU*)l, 16, 0, 0);
}

// ======== prep: projection (x<2048) + V transpose (x>=2048) ========
// phik pre-scaled by sqrt(ekn)/8 so d^2 = energy^2*ekn; ckn = 1e-5*ekn.
__global__ __launch_bounds__(256) void prep(
    const float* __restrict__ qg, const float* __restrict__ kg,
    const float* __restrict__ vg, const float* __restrict__ Wg,
    const float* __restrict__ bg,
    __half* __restrict__ phiq, __half* __restrict__ phik,
    __half* __restrict__ vt, float* __restrict__ ckn) {
  __shared__ __align__(16) float smem[64 * 68 + 64 * 64];
  const int x = blockIdx.x;
  const int tid = threadIdx.x;
  if (x >= 2048) {                       // ---- V transpose ----
    const int i = x - 2048;
    const int bh = i >> 5, s0 = (i & 31) * 64;
    float* t = smem;                     // [64][65]
    const float* base = vg + ((long)bh * SEQ + s0) * 64;
    #pragma unroll
    for (int i2 = 0; i2 < 4; ++i2) {
      int seg = i2 * 256 + tid;
      int srow = seg >> 4, sc4 = (seg & 15) << 2;
      float4 xv = *(const float4*)(base + srow * 64 + sc4);
      t[srow * 65 + sc4 + 0] = xv.x; t[srow * 65 + sc4 + 1] = xv.y;
      t[srow * 65 + sc4 + 2] = xv.z; t[srow * 65 + sc4 + 3] = xv.w;
    }
    __syncthreads();
    int d = tid >> 2, sc = (tid & 3) << 4;
    __half tmp[16];
    #pragma unroll
    for (int j = 0; j < 16; ++j) tmp[j] = __float2half(t[(sc + j) * 65 + d]);
    __half* dst = vt + ((long)bh * 64 + d) * SEQ + s0 + sc;
    *(uint4*)dst = *(uint4*)&tmp[0];
    *(uint4*)(dst + 8) = *(uint4*)&tmp[8];
    return;
  }
  // ---- projection ----
  const int wave = tid >> 6, lane = tid & 63;
  const int g = lane >> 4, ql = lane & 15;
  const int isk = x >= 1024;
  const long rowblk = (long)(x & 1023) * 64;
  const float* src = isk ? kg : qg;
  __half* dphi = isk ? phik : phiq;
  float* w_l = smem;                     // [64][68] W^T fp32
  float* x_l = smem + 64 * 68;

  #pragma unroll
  for (int i2 = 0; i2 < 4; ++i2) {       // stage W transposed
    int seg = i2 * 256 + tid;
    int d = seg >> 4, rc = (seg & 15) << 2;
    float4 wv = *(const float4*)(Wg + d * 64 + rc);
    w_l[(rc + 0) * 68 + d] = wv.x; w_l[(rc + 1) * 68 + d] = wv.y;
    w_l[(rc + 2) * 68 + d] = wv.z; w_l[(rc + 3) * 68 + d] = wv.w;
  }
  const float* xb = src + rowblk * 64;
  #pragma unroll
  for (int i2 = 0; i2 < 4; ++i2) {       // stage x (swizzled)
    int seg = i2 * 256 + tid;
    int row = seg >> 4;
    int off = ((seg & 15) * 4) ^ ((row & 7) << 2);
    gll16(xb + row * 64 + off, &x_l[seg * 4]);
  }
  float bias[4];
  #pragma unroll
  for (int rt = 0; rt < 4; ++rt) bias[rt] = bg[rt * 16 + ql];
  __syncthreads();

  f16x8 bh_[2][4], bl_[2][4];            // W hi/lo frags from LDS
  #pragma unroll
  for (int rt = 0; rt < 4; ++rt)
    #pragma unroll
    for (int ks = 0; ks < 2; ++ks) {
      f32x4 wa = *(const f32x4*)&w_l[(rt * 16 + ql) * 68 + ks * 32 + g * 8];
      f32x4 wb = *(const f32x4*)&w_l[(rt * 16 + ql) * 68 + ks * 32 + g * 8 + 4];
      #pragma unroll
      for (int j = 0; j < 4; ++j) {
        float w0 = wa[j]; _Float16 h0 = (_Float16)w0;
        bh_[ks][rt][j] = h0; bl_[ks][rt][j] = (_Float16)(w0 - (float)h0);
        float w1 = wb[j]; _Float16 h1 = (_Float16)w1;
        bh_[ks][rt][4 + j] = h1; bl_[ks][rt][4 + j] = (_Float16)(w1 - (float)h1);
      }
    }

  const int rl = wave * 16 + ql;
  float xv[16];
  #pragma unroll
  for (int ks = 0; ks < 2; ++ks)
    #pragma unroll
    for (int h = 0; h < 2; ++h) {
      int fi = (rl * 64 + ks * 32 + g * 8 + h * 4) ^ ((ql & 7) << 2);
      f32x4 u = *(const f32x4*)&x_l[fi];
      #pragma unroll
      for (int j = 0; j < 4; ++j) xv[ks * 8 + h * 4 + j] = u[j];
    }
  float nn = 0.f;
  #pragma unroll
  for (int j = 0; j < 16; ++j) nn = fmaf(xv[j], xv[j], nn);
  nn += __shfl_xor(nn, 16);
  nn += __shfl_xor(nn, 32);
  if (isk && g == 0) ckn[rowblk + rl] = 1e-5f * exp2f(nn * C1f);
  float scl = isk ? exp2f(nn * (C1f * 0.5f)) * 0.125f : 0.125f;
  float s4[4];
  #pragma unroll
  for (int i2 = 0; i2 < 4; ++i2) s4[i2] = __shfl(scl, (lane & 48) | (g * 4 + i2));

  f16x8 ah[2], al[2];
  #pragma unroll
  for (int ks = 0; ks < 2; ++ks)
    #pragma unroll
    for (int j = 0; j < 8; ++j) {
      float v = xv[ks * 8 + j];
      _Float16 hv = (_Float16)v;
      ah[ks][j] = hv;
      al[ks][j] = (_Float16)(v - (float)hv);
    }
  f32x4 sacc[4] = {};
  #pragma unroll
  for (int ks = 0; ks < 2; ++ks)
    #pragma unroll
    for (int rt = 0; rt < 4; ++rt) {
      sacc[rt] = __builtin_amdgcn_mfma_f32_16x16x32_f16(ah[ks], bh_[ks][rt], sacc[rt], 0, 0, 0);
      sacc[rt] = __builtin_amdgcn_mfma_f32_16x16x32_f16(al[ks], bh_[ks][rt], sacc[rt], 0, 0, 0);
      sacc[rt] = __builtin_amdgcn_mfma_f32_16x16x32_f16(ah[ks], bl_[ks][rt], sacc[rt], 0, 0, 0);
    }
  #pragma unroll
  for (int rt = 0; rt < 4; ++rt)
    #pragma unroll
    for (int i2 = 0; i2 < 4; ++i2) {
      float wq = sacc[rt][i2] + bias[rt];
      float sv, cv;
      __sincosf(wq, &sv, &cv);
      long row = rowblk + wave * 16 + g * 4 + i2;
      dphi[row * 128 + rt * 16 + ql] = __float2half(cv * s4[i2]);
      dphi[row * 128 + 64 + rt * 16 + ql] = __float2half(sv * s4[i2]);
    }
}

// ======== attn: r14 body + per-CU-balanced strip assignment ========
__global__ __launch_bounds__(256, 3) void attn_kernel(
    const __half* __restrict__ phiq_g, const __half* __restrict__ phik_g,
    const __half* __restrict__ vt_g, const float* __restrict__ ckn_g,
    float* __restrict__ out) {
  const int x = blockIdx.x;
  // CU-lifetime-constant bh (4 bh per XCD, L2-resident); per-CU strip quad
  // {31-u, 16+u, 15-u, u} sums to 62 -> every CU does exactly 66 block-steps.
  const int bh = ((x & 7) << 2) | ((x >> 3) & 3);
  const int u = (x >> 5) & 7;
  const int slot = x >> 8;
  const int s = (slot == 0) ? 31 - u : (slot == 1) ? 16 + u : (slot == 2) ? 15 - u : u;
  const int tid = threadIdx.x;
  const int wv = tid >> 6, lane = tid & 63;
  const int g = lane >> 4, ql = lane & 15;
  const int qh = wv & 1, kh = wv >> 1;
  const long rowbase = (long)bh * SEQ;
  const int qbase = s * 64 + qh * 32;               // wave's 32 q-rows

  __shared__ __align__(16) char smem[49152];
  __half* phik_l = (__half*)smem;                   // 2 x 8192 halves
  __half* vt_l = (__half*)(smem + 32768);           // 2 x 4096 halves

  const __half* pkb = phik_g + rowbase * 128;
  const __half* vtb = vt_g + (long)bh * 64 * SEQ;
  const float* ckp = ckn_g + rowbase + kh * 32 + g * 8;

  // ---- precomputed per-lane staging offsets (constant across all steps) ----
  // sigma (kh-split): LDS row rho=[kh|kt|g1 g0|r1 r0] holds key [kh|g1 g0|kt|r1 r0]
  unsigned koffv[4], kdstv[4], voffv[2], vdstv[2];
  #pragma unroll
  for (int i = 0; i < 4; ++i) {
    int seg = i * 256 + tid;
    int rho = seg >> 4;
    int sg = (rho & 32) | ((rho & 12) << 1) | ((rho & 16) >> 2) | (rho & 3);
    int off = ((seg & 15) * 8) ^ ((rho & 15) << 3);
    koffv[i] = sg * 128 + off;
    kdstv[i] = seg * 8;
  }
  #pragma unroll
  for (int i = 0; i < 2; ++i) {
    int seg = i * 256 + tid;
    int d = seg >> 3;
    int off = ((seg & 7) * 8) ^ ((d & 7) << 3);
    voffv[i] = d * SEQ + off;
    vdstv[i] = seg * 8;
  }

  // bb is always a literal at call sites -> static LDS offsets after inlining
  auto stageKV = [&](int tn, int bb) {
    const __half* kb = pkb + (long)tn * 8192;
    #pragma unroll
    for (int i = 0; i < 4; ++i) gll16(kb + koffv[i], phik_l + bb * 8192 + kdstv[i]);
    const __half* vb = vtb + tn * 64;
    #pragma unroll
    for (int i = 0; i < 2; ++i) gll16(vb + voffv[i], vt_l + bb * 4096 + vdstv[i]);
  };

  stageKV(0, 0);

  f16x8 bq[2][4];
  #pragma unroll
  for (int c = 0; c < 2; ++c)
    #pragma unroll
    for (int ks = 0; ks < 4; ++ks)
      bq[c][ks] = *(const f16x8*)(phiq_g + (rowbase + qbase + c * 16 + ql) * 128 + ks * 32 + g * 8);

  float lsum[2] = {0.f, 0.f};
  f32x4 acc[2][4] = {};

  auto step = [&](int t, int bb) {
    // One barrier per step: stage(t)->bb complete; all waves done reading bb^1.
    asm volatile("s_waitcnt vmcnt(0)" ::: "memory");
    __builtin_amdgcn_s_barrier();
    __builtin_amdgcn_sched_barrier(0);

    // ck loads first (oldest in vmcnt FIFO -> their wait leaves staging in flight)
    const float* ckt = ckp + t * 64;
    f32x4 ckA = *(const f32x4*)(ckt);
    f32x4 ckB = *(const f32x4*)(ckt + 4);
    __builtin_amdgcn_sched_barrier(0);
    if (t < s) stageKV(t + 1, bb ^ 1);
    __builtin_amdgcn_sched_barrier(0);

    const bool skip = (qbase + 31) < (t * 64 + kh * 32);
    if (!skip) {
      f32x4 sS[2][2] = {};
      __builtin_amdgcn_s_setprio(1);
      #pragma unroll
      for (int ks = 0; ks < 4; ++ks) {
        int i0 = (bb * 8192 + (kh * 32 + ql) * 128 + ks * 32 + g * 8) ^ (ql << 3);
        int i1 = (bb * 8192 + (kh * 32 + 16 + ql) * 128 + ks * 32 + g * 8) ^ (ql << 3);
        f16x8 a0 = *(const f16x8*)&phik_l[i0];
        f16x8 a1 = *(const f16x8*)&phik_l[i1];
        sS[0][0] = __builtin_amdgcn_mfma_f32_16x16x32_f16(a0, bq[0][ks], sS[0][0], 0, 0, 0);
        sS[0][1] = __builtin_amdgcn_mfma_f32_16x16x32_f16(a1, bq[0][ks], sS[0][1], 0, 0, 0);
        sS[1][0] = __builtin_amdgcn_mfma_f32_16x16x32_f16(a0, bq[1][ks], sS[1][0], 0, 0, 0);
        sS[1][1] = __builtin_amdgcn_mfma_f32_16x16x32_f16(a1, bq[1][ks], sS[1][1], 0, 0, 0);
      }
      __builtin_amdgcn_s_setprio(0);

      f16x8 pa[2];
      #pragma unroll
      for (int c = 0; c < 2; ++c) {
        const int qrow = qbase + c * 16 + ql;
        const bool domask = (t * 64 + kh * 32 + 31) > (qbase + c * 16);
        float e[8];
        #pragma unroll
        for (int kt = 0; kt < 2; ++kt)
          #pragma unroll
          for (int r = 0; r < 4; ++r) {
            float dd = sS[c][kt][r];
            float pe = fmaf(dd, dd, kt ? ckB[r] : ckA[r]);
            if (domask) {
              int key = t * 64 + kh * 32 + g * 8 + kt * 4 + r;
              pe = (key <= qrow) ? pe : 0.f;
            }
            e[kt * 4 + r] = pe;
          }
        lsum[c] += ((e[0] + e[1]) + (e[2] + e[3])) + ((e[4] + e[5]) + (e[6] + e[7]));
        U16 A;
        A.h[0] = __builtin_amdgcn_cvt_pkrtz(e[0], e[1]);
        A.h[1] = __builtin_amdgcn_cvt_pkrtz(e[2], e[3]);
        A.h[2] = __builtin_amdgcn_cvt_pkrtz(e[4], e[5]);
        A.h[3] = __builtin_amdgcn_cvt_pkrtz(e[6], e[7]);
        pa[c] = A.v;
      }

      __builtin_amdgcn_s_setprio(1);
      #pragma unroll
      for (int dt = 0; dt < 4; ++dt) {
        int idx = (bb * 4096 + (dt * 16 + ql) * 64 + kh * 32 + g * 8) ^ ((ql & 7) << 3);
        f16x8 bv = *(const f16x8*)&vt_l[idx];
        acc[0][dt] = __builtin_amdgcn_mfma_f32_16x16x32_f16(pa[0], bv, acc[0][dt], 0, 0, 0);
        acc[1][dt] = __builtin_amdgcn_mfma_f32_16x16x32_f16(pa[1], bv, acc[1][dt], 0, 0, 0);
      }
      __builtin_amdgcn_s_setprio(0);
    }
  };

  for (int t = 0; t <= s; t += 2) {
    step(t, 0);                          // inlined with literal bb=0
    if (t + 1 <= s) step(t + 1, 1);      // inlined with literal bb=1
  }

  // ---- epilogue: merge kh halves (exact adds; no max state), normalize, store ----
  float* dump = (float*)smem;               // 2 x 34 x 64 floats = 17 KB
  __syncthreads();
  if (kh) {
    #pragma unroll
    for (int c = 0; c < 2; ++c) {
      #pragma unroll
      for (int dt = 0; dt < 4; ++dt)
        #pragma unroll
        for (int r = 0; r < 4; ++r)
          dump[(qh * 34 + c * 16 + dt * 4 + r) * 64 + lane] = acc[c][dt][r];
      dump[(qh * 34 + 32 + c) * 64 + lane] = lsum[c];
    }
  }
  __syncthreads();
  if (!kh) {
    #pragma unroll
    for (int c = 0; c < 2; ++c) {
      lsum[c] += dump[(qh * 34 + 32 + c) * 64 + lane];
      lsum[c] += __shfl_xor(lsum[c], 16);
      lsum[c] += __shfl_xor(lsum[c], 32);
      #pragma unroll
      for (int dt = 0; dt < 4; ++dt)
        #pragma unroll
        for (int r = 0; r < 4; ++r)
          acc[c][dt][r] += dump[(qh * 34 + c * 16 + dt * 4 + r) * 64 + lane];
    }
    #pragma unroll
    for (int c = 0; c < 2; ++c)
      #pragma unroll
      for (int r = 0; r < 4; ++r) {
        float ls = __shfl(lsum[c], (lane & 48) | (g * 4 + r));
        float inv = __builtin_amdgcn_rcpf(ls);
        float* o = out + (rowbase + qbase + c * 16 + g * 4 + r) * 64 + ql;
        #pragma unroll
        for (int dt = 0; dt < 4; ++dt) o[dt * 16] = acc[c][dt][r] * inv;
      }
  }
}

extern "C" void kernel_launch(void* const* d_in, const int* in_sizes, int n_in,
                              void* d_out, int out_size, void* d_ws, size_t ws_size,
                              hipStream_t stream) {
  const float* q = (const float*)d_in[0];
  const float* k = (const float*)d_in[1];
  const float* v = (const float*)d_in[2];
  // d_in[3] = causal mask (applied analytically)
  const float* W = (const float*)d_in[4];
  const float* b = (const float*)d_in[5];
  float* out = (float*)d_out;

  char* ws = (char*)d_ws;
  __half* phiq = (__half*)ws;                          // 16 MB
  __half* phik = (__half*)(ws + 16777216);             // 16 MB
  __half* vt = (__half*)(ws + 33554432);               // 8 MB
  float* ckn = (float*)(ws + 41943040);                // 256 KB

  prep<<<dim3(3072), 256, 0, stream>>>(q, k, v, W, b, phiq, phik, vt, ckn);
  attn_kernel<<<dim3(1024), 256, 0, stream>>>(phiq, phik, vt, ckn, out);
}